// Round 1
// baseline (494.730 us; speedup 1.0000x reference)
//
#include <hip/hip_runtime.h>

// MaskedLightAdaIN: x [16,64,256,256] f32, mask [16,1,256,256] f32.
// Per (b,c): masked mean/unbiased-std over HW for fg (mask>=0.5) and bg,
// out = fg ? x : (x - mu_bg)/(sig_bg+EPS)*sig_fg + mu_fg.
//
// Pass 1: per-slice moments (one-pass: sum, sumsq, count; bg = total - fg).
// Pass 2: elementwise apply. Both float4-vectorized; mask re-reads hit L2.

#define HW    65536   // 256*256
#define HW4   16384   // HW/4
#define C     64
#define B     16
#define NSLICE (B * C)       // 1024
#define TOTAL4 (NSLICE * HW4) // 16,777,216 float4s

__global__ __launch_bounds__(512) void stats_kernel(
    const float* __restrict__ x, const float* __restrict__ mask,
    float4* __restrict__ stats) {
  const int slice = blockIdx.x;        // b*64 + c
  const int b = slice >> 6;
  const float4* __restrict__ x4 = (const float4*)(x + (size_t)slice * HW);
  const float4* __restrict__ m4 = (const float4*)(mask + (size_t)b * HW);

  float cnt = 0.f, sf = 0.f, s2f = 0.f, st = 0.f, s2t = 0.f;

#pragma unroll 4
  for (int i = threadIdx.x; i < HW4; i += 512) {
    float4 xv = x4[i];
    float4 mv = m4[i];
    const float* xe = (const float*)&xv;
    const float* me = (const float*)&mv;
#pragma unroll
    for (int k = 0; k < 4; ++k) {
      float xk = xe[k];
      float x2 = xk * xk;
      bool fg = me[k] >= 0.5f;
      st  += xk;
      s2t += x2;
      cnt += fg ? 1.f : 0.f;
      sf  += fg ? xk : 0.f;
      s2f += fg ? x2 : 0.f;
    }
  }

  // wave (64-lane) butterfly reduction
#pragma unroll
  for (int off = 32; off > 0; off >>= 1) {
    cnt += __shfl_down(cnt, off);
    sf  += __shfl_down(sf,  off);
    s2f += __shfl_down(s2f, off);
    st  += __shfl_down(st,  off);
    s2t += __shfl_down(s2t, off);
  }

  __shared__ float red[8][5];
  const int wave = threadIdx.x >> 6;
  const int lane = threadIdx.x & 63;
  if (lane == 0) {
    red[wave][0] = cnt; red[wave][1] = sf; red[wave][2] = s2f;
    red[wave][3] = st;  red[wave][4] = s2t;
  }
  __syncthreads();

  if (threadIdx.x == 0) {
    float tcnt = 0.f, tsf = 0.f, ts2f = 0.f, tst = 0.f, ts2t = 0.f;
#pragma unroll
    for (int w = 0; w < 8; ++w) {
      tcnt += red[w][0]; tsf += red[w][1]; ts2f += red[w][2];
      tst  += red[w][3]; ts2t += red[w][4];
    }
    float n_fg = tcnt;
    float n_bg = (float)HW - tcnt;
    float s_bg  = tst  - tsf;
    float s2_bg = ts2t - ts2f;

    float mu_fg  = tsf / fmaxf(n_fg, 1.f);
    float var_fg = fmaxf((ts2f - n_fg * mu_fg * mu_fg) / fmaxf(n_fg - 1.f, 1.f), 0.f);
    float sig_fg = sqrtf(var_fg);

    float mu_bg  = s_bg / fmaxf(n_bg, 1.f);
    float var_bg = fmaxf((s2_bg - n_bg * mu_bg * mu_bg) / fmaxf(n_bg - 1.f, 1.f), 0.f);
    float sig_bg = sqrtf(var_bg);

    float A = sig_fg / (sig_bg + 1e-8f);
    stats[slice] = make_float4(A, mu_bg, mu_fg, 0.f);
  }
}

__global__ __launch_bounds__(256) void apply_kernel(
    const float* __restrict__ x, const float* __restrict__ mask,
    const float4* __restrict__ stats, float* __restrict__ out) {
  const float4* __restrict__ x4 = (const float4*)x;
  const float4* __restrict__ m4 = (const float4*)mask;
  float4* __restrict__ o4 = (float4*)out;

  const int stride = gridDim.x * blockDim.x;
  for (int i = blockIdx.x * blockDim.x + threadIdx.x; i < TOTAL4; i += stride) {
    const int slice = i >> 14;            // / HW4
    const int b = slice >> 6;
    const int in_slice = i & (HW4 - 1);
    float4 stv = stats[slice];            // A, mu_bg, mu_fg
    float4 xv = x4[i];
    float4 mv = m4[(b << 14) + in_slice];
    float4 ov;
    float* oe = (float*)&ov;
    const float* xe = (const float*)&xv;
    const float* me = (const float*)&mv;
#pragma unroll
    for (int k = 0; k < 4; ++k) {
      float xk = xe[k];
      float h = fmaf(xk - stv.y, stv.x, stv.z);
      oe[k] = (me[k] >= 0.5f) ? xk : h;
    }
    o4[i] = ov;
  }
}

extern "C" void kernel_launch(void* const* d_in, const int* in_sizes, int n_in,
                              void* d_out, int out_size, void* d_ws, size_t ws_size,
                              hipStream_t stream) {
  const float* x = (const float*)d_in[0];
  const float* mask = (const float*)d_in[1];
  float* out = (float*)d_out;
  float4* stats = (float4*)d_ws;   // NSLICE float4s = 16 KiB

  stats_kernel<<<NSLICE, 512, 0, stream>>>(x, mask, stats);
  apply_kernel<<<8192, 256, 0, stream>>>(x, mask, stats, out);
}